// Round 1
// baseline (567.724 us; speedup 1.0000x reference)
//
#include <hip/hip_runtime.h>
#include <cstdint>
#include <cstddef>

#define BDIM 2
#define NQ 512
#define NEXP 256
#define MDIM 768
#define HN 48
#define DD 16
#define ED 768

// ---------------------------------------------------------------------------
// prep: wve[h][k] = sum_d w_force[h*16+d] * Wv[(h*16+d)*E + k]
//       ube[h]    = sum_d w_force[h*16+d] * bv[h*16+d]
// ---------------------------------------------------------------------------
__global__ void prep_kernel(const float* __restrict__ Wv, const float* __restrict__ bv,
                            const float* __restrict__ wf,
                            float* __restrict__ wve, float* __restrict__ ube) {
  int h = blockIdx.x;
  float wl[DD];
#pragma unroll
  for (int d = 0; d < DD; ++d) wl[d] = wf[h * DD + d];
  for (int k = threadIdx.x; k < ED; k += blockDim.x) {
    float s = 0.f;
#pragma unroll
    for (int d = 0; d < DD; ++d) s = fmaf(wl[d], Wv[(size_t)(h * DD + d) * ED + k], s);
    wve[(size_t)h * ED + k] = s;
  }
  if (threadIdx.x == 0) {
    float s = 0.f;
#pragma unroll
    for (int d = 0; d < DD; ++d) s = fmaf(wl[d], bv[h * DD + d], s);
    ube[h] = s;
  }
}

// ---------------------------------------------------------------------------
// proj: one GEMM out[1024 x 1584] = query[1024x768] @ [Wq; Wk; wve]^T
//   cols 0..767    -> qs[b][n][c]           = (dot + bq[c]) * 0.25
//   cols 768..1535 -> ke[(b*H+h)*16+d][n]   = dot + bk      (transposed k for LDS)
//   cols 1536..1583-> ub[(b*H+h)][n]        = dot + ube[h]
// ---------------------------------------------------------------------------
__global__ __launch_bounds__(256) void proj_kernel(
    const float* __restrict__ A,
    const float* __restrict__ Wq, const float* __restrict__ bq,
    const float* __restrict__ Wk, const float* __restrict__ bk,
    const float* __restrict__ wve, const float* __restrict__ ube,
    float* __restrict__ qs, float* __restrict__ ke, float* __restrict__ ub) {
  __shared__ __align__(16) float As[32][68];
  __shared__ __align__(16) float Bs[32][68];
  const int tid = threadIdx.x;
  const int tx = tid & 15, ty = tid >> 4;
  const int row0 = blockIdx.y * 64;
  const int col0 = blockIdx.x * 64;
  float acc[4][4] = {};
  for (int k0 = 0; k0 < ED; k0 += 32) {
    for (int f = tid; f < 512; f += 256) {
      int r = f >> 3, kq = f & 7;
      float4 v = *(const float4*)&A[(size_t)(row0 + r) * ED + k0 + kq * 4];
      As[kq * 4 + 0][r] = v.x; As[kq * 4 + 1][r] = v.y;
      As[kq * 4 + 2][r] = v.z; As[kq * 4 + 3][r] = v.w;
    }
    for (int f = tid; f < 512; f += 256) {
      int cc = f >> 3, kq = f & 7;
      int c = col0 + cc;
      float4 v = make_float4(0.f, 0.f, 0.f, 0.f);
      if (c < 1584) {
        const float* src;
        if (c < 768) src = Wq + (size_t)c * ED;
        else if (c < 1536) src = Wk + (size_t)(c - 768) * ED;
        else src = wve + (size_t)(c - 1536) * ED;
        v = *(const float4*)&src[k0 + kq * 4];
      }
      Bs[kq * 4 + 0][cc] = v.x; Bs[kq * 4 + 1][cc] = v.y;
      Bs[kq * 4 + 2][cc] = v.z; Bs[kq * 4 + 3][cc] = v.w;
    }
    __syncthreads();
#pragma unroll
    for (int kk = 0; kk < 32; ++kk) {
      float4 a4 = *(const float4*)&As[kk][ty * 4];
      float4 b4 = *(const float4*)&Bs[kk][tx * 4];
      float av[4] = {a4.x, a4.y, a4.z, a4.w};
      float bw[4] = {b4.x, b4.y, b4.z, b4.w};
#pragma unroll
      for (int i = 0; i < 4; ++i)
#pragma unroll
        for (int j = 0; j < 4; ++j) acc[i][j] = fmaf(av[i], bw[j], acc[i][j]);
    }
    __syncthreads();
  }
#pragma unroll
  for (int i = 0; i < 4; ++i) {
    int r = row0 + ty * 4 + i;
    int b = r >> 9, n = r & 511;
#pragma unroll
    for (int j = 0; j < 4; ++j) {
      int c = col0 + tx * 4 + j;
      if (c >= 1584) continue;
      float val = acc[i][j];
      if (c < 768) {
        qs[(size_t)(b * NQ + n) * ED + c] = (val + bq[c]) * 0.25f;
      } else if (c < 1536) {
        int ck = c - 768;
        int hh = ck >> 4, dd = ck & 15;
        ke[(size_t)((b * HN + hh) * DD + dd) * MDIM + n] = val + bk[ck];
      } else {
        int hh = c - 1536;
        ub[(size_t)(b * HN + hh) * MDIM + n] = val + ube[hh];
      }
    }
  }
}

// ---------------------------------------------------------------------------
// gather: fill m in [512,768) of ke / ub via outcell_index
// ---------------------------------------------------------------------------
__global__ void gather_kernel(const int* __restrict__ idx, float* __restrict__ ke,
                              float* __restrict__ ub) {
  const int id = blockIdx.x * 256 + threadIdx.x;
  const int N1 = BDIM * HN * DD * NEXP;  // 393216
  if (id < N1) {
    int j = id & (NEXP - 1);
    int d = (id >> 8) & (DD - 1);
    int hb = id >> 12;                   // b*48 + h, 0..95
    int n = idx[(hb / HN) * NEXP + j];
    float* row = ke + (size_t)(hb * DD + d) * MDIM;
    row[NQ + j] = row[n];
  } else {
    int id2 = id - N1;
    if (id2 < BDIM * HN * NEXP) {
      int j = id2 & (NEXP - 1);
      int hb = id2 >> 8;                 // b*48 + h
      int n = idx[(hb / HN) * NEXP + j];
      float* row = ub + (size_t)hb * MDIM;
      row[NQ + j] = row[n];
    }
  }
}

// ---------------------------------------------------------------------------
// fused attention: block = (b, h, 64-query tile). K_h transposed in LDS.
// Each wave processes 4 query rows jointly (full m-row in registers),
// wave-shuffle softmax, e*u*delta reduction -> 3 atomicAdds per (b,h,n).
// ---------------------------------------------------------------------------
__device__ __forceinline__ void fma4(float4& a, float q, const float4& k) {
  a.x = fmaf(q, k.x, a.x); a.y = fmaf(q, k.y, a.y);
  a.z = fmaf(q, k.z, a.z); a.w = fmaf(q, k.w, a.w);
}

__global__ __launch_bounds__(256, 3) void fused_kernel(
    const float* __restrict__ qs, const float* __restrict__ ke, const float* __restrict__ ub,
    const float* __restrict__ bias, const float* __restrict__ dp, float* __restrict__ out) {
  __shared__ __align__(16) float kT[DD * MDIM];   // 48 KB, layout [d][m]
  __shared__ __align__(16) float us[MDIM];        // 3 KB
  const int bid = blockIdx.x;
  // XCD-locality swizzle: bid%8 ~ XCD. Map each (tile,b) combo to one XCD so
  // the 48x delta_pos reuse stays in that XCD's L2.
  const int xcd = bid & 7;
  const int s = bid >> 3;                       // 0..95
  const int combo = xcd + ((s >= HN) ? 8 : 0);  // 0..15 == t*2 + b
  const int h = (s >= HN) ? (s - HN) : s;
  const int t = combo >> 1;
  const int b = combo & 1;

  {
    const float4* src = (const float4*)(ke + (size_t)(b * HN + h) * DD * MDIM);
    float4* dst = (float4*)kT;
    for (int i = threadIdx.x; i < DD * MDIM / 4; i += 256) dst[i] = src[i];
    const float4* usrc = (const float4*)(ub + (size_t)(b * HN + h) * MDIM);
    float4* ud = (float4*)us;
    for (int i = threadIdx.x; i < MDIM / 4; i += 256) ud[i] = usrc[i];
  }
  __syncthreads();

  const int wave = threadIdx.x >> 6;
  const int lane = threadIdx.x & 63;

  const float4* us4 = (const float4*)us;
  const float4 u0 = us4[lane], u1 = us4[lane + 64], u2 = us4[lane + 128];

  for (int it = 0; it < 4; ++it) {
    const int n0 = t * 64 + wave * 16 + it * 4;
    float4 qv[4][4];
#pragma unroll
    for (int qi = 0; qi < 4; ++qi) {
      const float4* qp = (const float4*)(qs + (size_t)(b * NQ + n0 + qi) * ED + h * DD);
#pragma unroll
      for (int x = 0; x < 4; ++x) qv[qi][x] = qp[x];
    }
    float4 a[4][3];
#pragma unroll
    for (int qi = 0; qi < 4; ++qi) {
      const float4* bp = (const float4*)(bias + (size_t)((b * HN + h) * NQ + n0 + qi) * MDIM);
#pragma unroll
      for (int j = 0; j < 3; ++j) a[qi][j] = bp[lane + 64 * j];
    }
    // attn += q_d * kT[d][m]
#pragma unroll
    for (int x = 0; x < 4; ++x) {
#pragma unroll
      for (int d4 = 0; d4 < 4; ++d4) {
        const int d = x * 4 + d4;
        const float4* kr = (const float4*)(kT + d * MDIM);
        const float4 k0 = kr[lane], k1 = kr[lane + 64], k2 = kr[lane + 128];
#pragma unroll
        for (int qi = 0; qi < 4; ++qi) {
          const float qd = (d4 == 0) ? qv[qi][x].x : (d4 == 1) ? qv[qi][x].y
                          : (d4 == 2) ? qv[qi][x].z : qv[qi][x].w;
          fma4(a[qi][0], qd, k0);
          fma4(a[qi][1], qd, k1);
          fma4(a[qi][2], qd, k2);
        }
      }
    }
#pragma unroll
    for (int qi = 0; qi < 4; ++qi) {
      float mx = -1e30f;
#pragma unroll
      for (int j = 0; j < 3; ++j)
        mx = fmaxf(mx, fmaxf(fmaxf(a[qi][j].x, a[qi][j].y), fmaxf(a[qi][j].z, a[qi][j].w)));
#pragma unroll
      for (int sh = 32; sh > 0; sh >>= 1) mx = fmaxf(mx, __shfl_xor(mx, sh));
      float e[12];
#pragma unroll
      for (int j = 0; j < 3; ++j) {
        e[j * 4 + 0] = __expf(a[qi][j].x - mx);
        e[j * 4 + 1] = __expf(a[qi][j].y - mx);
        e[j * 4 + 2] = __expf(a[qi][j].z - mx);
        e[j * 4 + 3] = __expf(a[qi][j].w - mx);
      }
      float l = 0.f;
#pragma unroll
      for (int k = 0; k < 12; ++k) l += e[k];
      const float* dpp = dp + (size_t)(b * NQ + n0 + qi) * MDIM * 3;
      float f0 = 0.f, f1 = 0.f, f2 = 0.f;
#pragma unroll
      for (int j = 0; j < 3; ++j) {
        const int m0 = j * 256 + lane * 4;
        const float4* dv = (const float4*)(dpp + (size_t)m0 * 3);
        const float4 d0 = dv[0], d1 = dv[1], d2 = dv[2];
        const float4 uu = (j == 0) ? u0 : (j == 1) ? u1 : u2;
        const float w0 = e[j * 4 + 0] * uu.x;
        const float w1 = e[j * 4 + 1] * uu.y;
        const float w2 = e[j * 4 + 2] * uu.z;
        const float w3 = e[j * 4 + 3] * uu.w;
        f0 = fmaf(w0, d0.x, f0); f0 = fmaf(w1, d0.w, f0); f0 = fmaf(w2, d1.z, f0); f0 = fmaf(w3, d2.y, f0);
        f1 = fmaf(w0, d0.y, f1); f1 = fmaf(w1, d1.x, f1); f1 = fmaf(w2, d1.w, f1); f1 = fmaf(w3, d2.z, f1);
        f2 = fmaf(w0, d0.z, f2); f2 = fmaf(w1, d1.y, f2); f2 = fmaf(w2, d2.x, f2); f2 = fmaf(w3, d2.w, f2);
      }
#pragma unroll
      for (int sh = 32; sh > 0; sh >>= 1) {
        l += __shfl_xor(l, sh);
        f0 += __shfl_xor(f0, sh);
        f1 += __shfl_xor(f1, sh);
        f2 += __shfl_xor(f2, sh);
      }
      if (lane == 0) {
        const float inv = 1.0f / l;
        float* op = out + (size_t)(b * NQ + n0 + qi) * 3;
        atomicAdd(op + 0, f0 * inv);
        atomicAdd(op + 1, f1 * inv);
        atomicAdd(op + 2, f2 * inv);
      }
    }
  }
}

// ---------------------------------------------------------------------------
extern "C" void kernel_launch(void* const* d_in, const int* in_sizes, int n_in,
                              void* d_out, int out_size, void* d_ws, size_t ws_size,
                              hipStream_t stream) {
  const float* query     = (const float*)d_in[0];
  const float* attn_bias = (const float*)d_in[1];
  const float* delta_pos = (const float*)d_in[2];
  const int*   outcell   = (const int*)d_in[3];
  const float* Wq = (const float*)d_in[4];
  const float* bq = (const float*)d_in[5];
  const float* Wk = (const float*)d_in[6];
  const float* bk = (const float*)d_in[7];
  const float* Wv = (const float*)d_in[8];
  const float* bv = (const float*)d_in[9];
  const float* wf = (const float*)d_in[10];
  float* out = (float*)d_out;
  float* ws  = (float*)d_ws;

  // workspace layout (floats): total ~2.08M floats = 8.3 MB
  float* wve = ws;                                  // 48*768
  float* ube = ws + 36864;                          // 48 (padded to 64)
  float* qsb = ws + 36928;                          // 2*512*768
  float* keb = qsb + (size_t)BDIM * NQ * ED;        // 2*48*16*768
  float* ubb = keb + (size_t)BDIM * HN * DD * MDIM; // 2*48*768

  hipMemsetAsync(d_out, 0, (size_t)out_size * sizeof(float), stream);
  prep_kernel<<<HN, 256, 0, stream>>>(Wv, bv, wf, wve, ube);
  proj_kernel<<<dim3(25, 16), 256, 0, stream>>>(query, Wq, bq, Wk, bk, wve, ube,
                                                qsb, keb, ubb);
  gather_kernel<<<1632, 256, 0, stream>>>(outcell, keb, ubb);
  fused_kernel<<<768, 256, 0, stream>>>(qsb, keb, ubb, attn_bias, delta_pos, out);
}